// Round 1
// 826.962 us; speedup vs baseline: 1.0812x; 1.0812x over previous
//
#include <hip/hip_runtime.h>
#include <math.h>

#define B_ 64
#define N_ 4096
#define D_ 128
#define S_ 7
#define H_ 256
#define ITERS_ 3
#define AP 132   // padded fp32 LDS row stride (other kernels)
#define WLDA 136 // padded bf16 LDS row stride for k_lnkv A-tile (136*2B=272B, 16B aligned, breaks bank conflicts)

__device__ __forceinline__ float dot4(float4 a, float4 b) {
  return a.x * b.x + a.y * b.y + a.z * b.z + a.w * b.w;
}
__device__ __forceinline__ float4 ld4(const float* p) {
  return *reinterpret_cast<const float4*>(p);
}

typedef __attribute__((ext_vector_type(8))) short bf16x8;
typedef __attribute__((ext_vector_type(4))) float f32x4;

// round-to-nearest-even f32 -> bf16 bits
__device__ __forceinline__ ushort f2bf(float x) {
  unsigned u = __float_as_uint(x);
  u += 0x7fffu + ((u >> 16) & 1u);
  return (ushort)(u >> 16);
}
__device__ __forceinline__ float bf2f(ushort b) {
  return __uint_as_float(((unsigned)b) << 16);
}

// ---------------- K0: slots = mu + sigma * noise ----------------
__global__ void k_init(const float* __restrict__ noise, const float* __restrict__ mu,
                       const float* __restrict__ sigma, float* __restrict__ slots) {
  int idx = blockIdx.x * 256 + threadIdx.x;  // 57344 total
  int d = idx & 127;
  slots[idx] = mu[d] + sigma[d] * noise[idx];
}

// ---------------- K0b: split Wk/Wv into bf16 hi/lo (runs once, ~2us) ----------------
// Layout in wsp (ushort): [0:16384)=Wk_hi [16384:32768)=Wk_lo [32768:49152)=Wv_hi [49152:65536)=Wv_lo
__global__ void k_wsplit(const float* __restrict__ Wk, const float* __restrict__ Wv,
                         ushort* __restrict__ wsp) {
  int i = blockIdx.x * 256 + threadIdx.x;  // 16384 total
  float k = Wk[i], v = Wv[i];
  ushort kh = f2bf(k);
  ushort vh = f2bf(v);
  wsp[i] = kh;
  wsp[16384 + i] = f2bf(k - bf2f(kh));
  wsp[32768 + i] = vh;
  wsp[49152 + i] = f2bf(v - bf2f(vh));
}

// ---------------- K1: LN(emb), keys = ln@Wk^T+bk, values = ln@Wv^T+bv ----------------
// bf16 MFMA with 2-term split precision: x ~= hi + lo (bf16 each);
// x.w = hi.wh + lo.wh + hi.wl  (drops lo.wl ~ 2^-18 rel).
// 64 rows/block, 4 waves; wave rg owns rows rg*16..+15 x all 256 output features.
// mfma(w_frag, a_frag, acc): D row-index (lane>>4)*4+reg = feature (4 consecutive -> float4 store),
// D col-index lane&15 = emb row.
__global__ __launch_bounds__(256) void k_lnkv(
    const float* __restrict__ emb, const ushort* __restrict__ wsp,
    const float* __restrict__ bk, const float* __restrict__ bv,
    const float* __restrict__ lng, const float* __restrict__ lnb,
    float* __restrict__ keys, float* __restrict__ values) {
  __shared__ __align__(16) ushort ah[64 * WLDA];
  __shared__ __align__(16) ushort al[64 * WLDA];
  int t = threadIdx.x;
  long rowbase = (long)blockIdx.x * 64;

  // stage + LN: 4 threads per row, 32 elems each; write bf16 hi/lo to LDS
  {
    int r = t >> 2;
    int io = (t & 3) * 32;
    const float* src = emb + (rowbase + r) * D_ + io;
    float4 xv[8];
    float sum = 0.f, sumsq = 0.f;
#pragma unroll
    for (int k = 0; k < 8; k++) {
      xv[k] = reinterpret_cast<const float4*>(src)[k];
      sum += xv[k].x + xv[k].y + xv[k].z + xv[k].w;
      sumsq += xv[k].x * xv[k].x + xv[k].y * xv[k].y + xv[k].z * xv[k].z + xv[k].w * xv[k].w;
    }
    sum += __shfl_xor(sum, 1, 4);   sum += __shfl_xor(sum, 2, 4);
    sumsq += __shfl_xor(sumsq, 1, 4); sumsq += __shfl_xor(sumsq, 2, 4);
    float mean = sum * (1.f / 128.f);
    float var = sumsq * (1.f / 128.f) - mean * mean;
    float rs = rsqrtf(var + 1e-5f);
#pragma unroll
    for (int k = 0; k < 8; k++) {
      float4 gv = reinterpret_cast<const float4*>(lng + io)[k];
      float4 bv4 = reinterpret_cast<const float4*>(lnb + io)[k];
      float ox = (xv[k].x - mean) * rs * gv.x + bv4.x;
      float oy = (xv[k].y - mean) * rs * gv.y + bv4.y;
      float oz = (xv[k].z - mean) * rs * gv.z + bv4.z;
      float ow = (xv[k].w - mean) * rs * gv.w + bv4.w;
      ushort4 h4, l4;
      h4.x = f2bf(ox); l4.x = f2bf(ox - bf2f(h4.x));
      h4.y = f2bf(oy); l4.y = f2bf(oy - bf2f(h4.y));
      h4.z = f2bf(oz); l4.z = f2bf(oz - bf2f(h4.z));
      h4.w = f2bf(ow); l4.w = f2bf(ow - bf2f(h4.w));
      *reinterpret_cast<ushort4*>(&ah[r * WLDA + io + k * 4]) = h4;
      *reinterpret_cast<ushort4*>(&al[r * WLDA + io + k * 4]) = l4;
    }
  }
  __syncthreads();

  int lane = t & 63, rg = t >> 6;
  int lr = lane & 15;   // frag minor index (W row / emb row)
  int lk = lane >> 4;   // k-group 0..3

  // hoist A (LN rows) fragments: 8 ds_read_b128 total
  bf16x8 afh[4], afl[4];
  {
    const ushort* prh = &ah[(rg * 16 + lr) * WLDA + lk * 8];
    const ushort* prl = &al[(rg * 16 + lr) * WLDA + lk * 8];
#pragma unroll
    for (int kk = 0; kk < 4; kk++) {
      afh[kk] = *reinterpret_cast<const bf16x8*>(prh + kk * 32);
      afl[kk] = *reinterpret_cast<const bf16x8*>(prl + kk * 32);
    }
  }

  const ushort* wk_hi = wsp;
  const ushort* wk_lo = wsp + 16384;
  const ushort* wv_hi = wsp + 32768;
  const ushort* wv_lo = wsp + 49152;

  f32x4 acc[16];
#pragma unroll
  for (int ct = 0; ct < 16; ct++) acc[ct] = (f32x4){0.f, 0.f, 0.f, 0.f};

#pragma unroll
  for (int ct = 0; ct < 16; ct++) {
    const ushort* whi = (ct < 8 ? wk_hi : wv_hi) + ((ct & 7) * 16 + lr) * D_ + lk * 8;
    const ushort* wlo = (ct < 8 ? wk_lo : wv_lo) + ((ct & 7) * 16 + lr) * D_ + lk * 8;
#pragma unroll
    for (int kk = 0; kk < 4; kk++) {
      bf16x8 wh = *reinterpret_cast<const bf16x8*>(whi + kk * 32);
      bf16x8 wl = *reinterpret_cast<const bf16x8*>(wlo + kk * 32);
      acc[ct] = __builtin_amdgcn_mfma_f32_16x16x32_bf16(wh, afh[kk], acc[ct], 0, 0, 0);
      acc[ct] = __builtin_amdgcn_mfma_f32_16x16x32_bf16(wh, afl[kk], acc[ct], 0, 0, 0);
      acc[ct] = __builtin_amdgcn_mfma_f32_16x16x32_bf16(wl, afh[kk], acc[ct], 0, 0, 0);
    }
  }

  // store: lane holds features (lk*4..lk*4+3) of emb row (rg*16+lr), per col-tile
  long row = rowbase + rg * 16 + lr;
#pragma unroll
  for (int ct = 0; ct < 16; ct++) {
    float* dst = (ct < 8) ? keys : values;
    const float* bias = (ct < 8) ? bk : bv;
    int c0 = (ct & 7) * 16 + lk * 4;
    float4 bb = ld4(bias + c0);
    float4 o = make_float4(acc[ct][0] + bb.x, acc[ct][1] + bb.y,
                           acc[ct][2] + bb.z, acc[ct][3] + bb.w);
    *reinterpret_cast<float4*>(&dst[row * D_ + c0]) = o;
  }
}

// ---------------- K2: q = LN(slots) @ Wq^T + bq ----------------
__global__ __launch_bounds__(128) void k_q(
    const float* __restrict__ slots, const float* __restrict__ Wq, const float* __restrict__ bq,
    const float* __restrict__ g, const float* __restrict__ b, float* __restrict__ q) {
  __shared__ __align__(16) float lns[AP];
  __shared__ float red[4];
  int row = blockIdx.x;  // b*7+s
  int d = threadIdx.x;
  float x = slots[row * D_ + d];
  float s1 = x, s2 = x * x;
#pragma unroll
  for (int off = 32; off >= 1; off >>= 1) { s1 += __shfl_down(s1, off); s2 += __shfl_down(s2, off); }
  if ((d & 63) == 0) { red[(d >> 6) * 2] = s1; red[(d >> 6) * 2 + 1] = s2; }
  __syncthreads();
  float sum = red[0] + red[2], sumsq = red[1] + red[3];
  float mean = sum * (1.f / 128.f);
  float var = sumsq * (1.f / 128.f) - mean * mean;
  float rs = rsqrtf(var + 1e-5f);
  lns[d] = (x - mean) * rs * g[d] + b[d];
  __syncthreads();
  const float* w = Wq + d * D_;
  float acc = bq[d];
  for (int i4 = 0; i4 < D_; i4 += 4) acc += dot4(*reinterpret_cast<const float4*>(&lns[i4]), ld4(w + i4));
  q[row * D_ + d] = acc;
}

// ---------------- K3a: logits[b][s][j] = q[b,s,:] . keys[b,j,:] ----------------
__global__ __launch_bounds__(256) void k_logits(
    const float* __restrict__ qbuf, const float* __restrict__ keys, float* __restrict__ logits) {
  __shared__ __align__(16) float qs[7 * AP];
  __shared__ __align__(16) float kt[64 * AP];
  __shared__ float red[28 * 64];  // [g*7+s][j]
  int t = threadIdx.x;
  int b = blockIdx.x >> 3, jc = blockIdx.x & 7;
  if (t < 224) {
    int s = t >> 5, i4 = (t & 31) * 4;
    *reinterpret_cast<float4*>(&qs[s * AP + i4]) =
        ld4(&qbuf[(b * 7 + s) * D_ + i4]);
  }
  int j = t & 63, g = t >> 6, ib = g * 32;
  for (int sub = 0; sub < 8; sub++) {
    int j0 = jc * 512 + sub * 64;
#pragma unroll
    for (int u = 0; u < 8; u++) {
      int f = u * 256 + t;
      int row = f >> 5, i4 = (f & 31) * 4;
      *reinterpret_cast<float4*>(&kt[row * AP + i4]) =
          ld4(&keys[((long)b * N_ + j0 + row) * D_ + i4]);
    }
    __syncthreads();
    float acc7[7];
#pragma unroll
    for (int s = 0; s < 7; s++) acc7[s] = 0.f;
#pragma unroll
    for (int st = 0; st < 8; st++) {
      float4 kv = *reinterpret_cast<const float4*>(&kt[j * AP + ib + st * 4]);
#pragma unroll
      for (int s = 0; s < 7; s++) {
        float4 qv = *reinterpret_cast<const float4*>(&qs[s * AP + ib + st * 4]);
        acc7[s] += dot4(kv, qv);
      }
    }
#pragma unroll
    for (int s = 0; s < 7; s++) red[(g * 7 + s) * 64 + j] = acc7[s];
    __syncthreads();
    for (int pp = t; pp < 448; pp += 256) {
      int s = pp >> 6, jj = pp & 63;
      float l = red[s * 64 + jj] + red[(7 + s) * 64 + jj] +
                red[(14 + s) * 64 + jj] + red[(21 + s) * 64 + jj];
      logits[(long)(b * 7 + s) * N_ + j0 + jj] = l;
    }
    __syncthreads();
  }
}

// ---------------- K3b: softmax over N, in place ----------------
// NOTE: reference's (softmax+1e-8)/renorm is a <=4.1e-5 relative perturbation -> skipped.
__global__ __launch_bounds__(256) void k_softmax(float* __restrict__ logits) {
  __shared__ float sm[4], ss[4];
  long base = (long)blockIdx.x * N_;
  int t = threadIdx.x;
  float4 v[4];
  float lmax = -1e30f;
#pragma unroll
  for (int p = 0; p < 4; p++) {
    v[p] = ld4(&logits[base + (p * 256 + t) * 4]);
    lmax = fmaxf(lmax, fmaxf(fmaxf(v[p].x, v[p].y), fmaxf(v[p].z, v[p].w)));
  }
#pragma unroll
  for (int off = 32; off >= 1; off >>= 1) lmax = fmaxf(lmax, __shfl_down(lmax, off));
  if ((t & 63) == 0) sm[t >> 6] = lmax;
  __syncthreads();
  float m = fmaxf(fmaxf(sm[0], sm[1]), fmaxf(sm[2], sm[3]));
  float lsum = 0.f;
#pragma unroll
  for (int p = 0; p < 4; p++) {
    v[p].x = __expf(v[p].x - m); v[p].y = __expf(v[p].y - m);
    v[p].z = __expf(v[p].z - m); v[p].w = __expf(v[p].w - m);
    lsum += v[p].x + v[p].y + v[p].z + v[p].w;
  }
#pragma unroll
  for (int off = 32; off >= 1; off >>= 1) lsum += __shfl_down(lsum, off);
  if ((t & 63) == 0) ss[t >> 6] = lsum;
  __syncthreads();
  float inv = 1.f / (ss[0] + ss[1] + ss[2] + ss[3]);
#pragma unroll
  for (int p = 0; p < 4; p++) {
    v[p].x *= inv; v[p].y *= inv; v[p].z *= inv; v[p].w *= inv;
    *reinterpret_cast<float4*>(&logits[base + (p * 256 + t) * 4]) = v[p];
  }
}

// ---------------- K3c: partialA[b][jc][s][d] = sum_{j in chunk} p[b,s,j] * values[b,j,d] ----------------
__global__ __launch_bounds__(256) void k_updates(
    const float* __restrict__ p, const float* __restrict__ values, float* __restrict__ partialA) {
  __shared__ __align__(16) float vt[64 * AP];  // reused as red[8][7][128] at the end
  __shared__ float pt[7 * 64];
  int t = threadIdx.x;
  int b = blockIdx.x >> 3, jc = blockIdx.x & 7;
  int d4 = (t & 31) * 4, jg = t >> 5;
  float acc[7][4];
#pragma unroll
  for (int s = 0; s < 7; s++)
#pragma unroll
    for (int c = 0; c < 4; c++) acc[s][c] = 0.f;

  for (int sub = 0; sub < 8; sub++) {
    int j0 = jc * 512 + sub * 64;
#pragma unroll
    for (int u = 0; u < 8; u++) {
      int f = u * 256 + t;
      int row = f >> 5, i4 = (f & 31) * 4;
      *reinterpret_cast<float4*>(&vt[row * AP + i4]) =
          ld4(&values[((long)b * N_ + j0 + row) * D_ + i4]);
    }
    for (int pp = t; pp < 448; pp += 256) {
      int s = pp >> 6, jj = pp & 63;
      pt[s * 64 + jj] = p[(long)(b * 7 + s) * N_ + j0 + jj];
    }
    __syncthreads();
#pragma unroll
    for (int jl = 0; jl < 8; jl++) {
      int jj = jg * 8 + jl;
      float4 vv = *reinterpret_cast<const float4*>(&vt[jj * AP + d4]);
#pragma unroll
      for (int s = 0; s < 7; s++) {
        float e = pt[s * 64 + jj];
        acc[s][0] += e * vv.x; acc[s][1] += e * vv.y;
        acc[s][2] += e * vv.z; acc[s][3] += e * vv.w;
      }
    }
    __syncthreads();
  }
  float* red = vt;
#pragma unroll
  for (int s = 0; s < 7; s++)
    *reinterpret_cast<float4*>(&red[(jg * 7 + s) * 128 + d4]) =
        make_float4(acc[s][0], acc[s][1], acc[s][2], acc[s][3]);
  __syncthreads();
  for (int pp = t; pp < 896; pp += 256) {
    int s = pp >> 7, d = pp & 127;
    float x = 0.f;
#pragma unroll
    for (int g = 0; g < 8; g++) x += red[(g * 7 + s) * 128 + d];
    partialA[((long)(b * 8 + jc) * 7 + s) * 128 + d] = x;
  }
}

// ---------------- K4: combine partials + GRUCell + LN + FFN (+residual), in-place on slots ----------------
__global__ __launch_bounds__(128) void k_gruff(
    const float* __restrict__ partialA, float* __restrict__ slots,
    const float* __restrict__ Wih, const float* __restrict__ Whh,
    const float* __restrict__ bih, const float* __restrict__ bhh,
    const float* __restrict__ W1, const float* __restrict__ b1,
    const float* __restrict__ W2, const float* __restrict__ b2,
    const float* __restrict__ gff, const float* __restrict__ bff) {
  __shared__ __align__(16) float xs[AP];
  __shared__ __align__(16) float hs[AP];
  __shared__ __align__(16) float lns[AP];
  __shared__ __align__(16) float h1s[H_];
  __shared__ float red4[4];
  int blk = blockIdx.x;
  int b = blk / 7, s = blk % 7;
  int d = threadIdx.x;

  float x = 0.f;
#pragma unroll
  for (int jc = 0; jc < 8; jc++) x += partialA[((long)(b * 8 + jc) * 7 + s) * 128 + d];
  float h = slots[blk * D_ + d];
  xs[d] = x; hs[d] = h;
  __syncthreads();

  float gir = bih[d], giz = bih[128 + d], gin = bih[256 + d];
  float ghr = bhh[d], ghz = bhh[128 + d], ghn = bhh[256 + d];
  const float* wir = Wih + d * D_;
  const float* wiz = Wih + (128 + d) * D_;
  const float* win = Wih + (256 + d) * D_;
  const float* whr = Whh + d * D_;
  const float* whz = Whh + (128 + d) * D_;
  const float* whn = Whh + (256 + d) * D_;
  for (int i4 = 0; i4 < D_; i4 += 4) {
    float4 xv = *reinterpret_cast<const float4*>(&xs[i4]);
    float4 hv = *reinterpret_cast<const float4*>(&hs[i4]);
    gir += dot4(xv, ld4(wir + i4)); giz += dot4(xv, ld4(wiz + i4)); gin += dot4(xv, ld4(win + i4));
    ghr += dot4(hv, ld4(whr + i4)); ghz += dot4(hv, ld4(whz + i4)); ghn += dot4(hv, ld4(whn + i4));
  }
  float r = 1.f / (1.f + __expf(-(gir + ghr)));
  float z = 1.f / (1.f + __expf(-(giz + ghz)));
  float n = tanhf(gin + r * ghn);
  float ns = (1.f - z) * n + z * h;

  float s1 = ns, s2 = ns * ns;
#pragma unroll
  for (int off = 32; off >= 1; off >>= 1) { s1 += __shfl_down(s1, off); s2 += __shfl_down(s2, off); }
  if ((d & 63) == 0) { red4[(d >> 6) * 2] = s1; red4[(d >> 6) * 2 + 1] = s2; }
  __syncthreads();
  float sum = red4[0] + red4[2], sumsq = red4[1] + red4[3];
  float mean = sum * (1.f / 128.f);
  float var = sumsq * (1.f / 128.f) - mean * mean;
  float rs = rsqrtf(var + 1e-5f);
  lns[d] = (ns - mean) * rs * gff[d] + bff[d];
  __syncthreads();

  float a0 = b1[d], a1 = b1[d + 128];
  const float* w1a = W1 + d * D_;
  const float* w1b = W1 + (128 + d) * D_;
  for (int i4 = 0; i4 < D_; i4 += 4) {
    float4 lv = *reinterpret_cast<const float4*>(&lns[i4]);
    a0 += dot4(lv, ld4(w1a + i4));
    a1 += dot4(lv, ld4(w1b + i4));
  }
  h1s[d] = fmaxf(a0, 0.f);
  h1s[d + 128] = fmaxf(a1, 0.f);
  __syncthreads();

  float f = b2[d];
  const float* w2r = W2 + d * H_;
  for (int h4 = 0; h4 < H_; h4 += 4)
    f += dot4(*reinterpret_cast<const float4*>(&h1s[h4]), ld4(w2r + h4));
  slots[blk * D_ + d] = ns + f;
}

extern "C" void kernel_launch(void* const* d_in, const int* in_sizes, int n_in,
                              void* d_out, int out_size, void* d_ws, size_t ws_size,
                              hipStream_t stream) {
  const float* emb   = (const float*)d_in[0];
  const float* noise = (const float*)d_in[1];
  const float* mu    = (const float*)d_in[2];
  const float* sigma = (const float*)d_in[3];
  const float* Wk = (const float*)d_in[4];  const float* bk = (const float*)d_in[5];
  const float* Wq = (const float*)d_in[6];  const float* bq = (const float*)d_in[7];
  const float* Wv = (const float*)d_in[8];  const float* bv = (const float*)d_in[9];
  const float* Wih = (const float*)d_in[10]; const float* Whh = (const float*)d_in[11];
  const float* bih = (const float*)d_in[12]; const float* bhh = (const float*)d_in[13];
  const float* W1 = (const float*)d_in[14];  const float* b1 = (const float*)d_in[15];
  const float* W2 = (const float*)d_in[16];  const float* b2 = (const float*)d_in[17];
  const float* lin_g = (const float*)d_in[18]; const float* lin_b = (const float*)d_in[19];
  const float* ls_g  = (const float*)d_in[20]; const float* ls_b  = (const float*)d_in[21];
  const float* lff_g = (const float*)d_in[22]; const float* lff_b = (const float*)d_in[23];

  float* slots = (float*)d_out;  // [B,S,D] lives in d_out, updated in place
  float* keys     = (float*)d_ws;                       // 33,554,432 f
  float* values   = keys + (size_t)B_ * N_ * D_;        // 33,554,432 f
  float* qbuf     = values + (size_t)B_ * N_ * D_;      // 57,344 f
  float* logits   = qbuf + (size_t)B_ * S_ * D_;        // 1,835,008 f
  float* partialA = logits + (size_t)B_ * S_ * N_;      // 458,752 f
  // W-split bf16 scratch (65536 ushort = 128KB) overlaps partialA: it is only
  // read by k_lnkv, which completes before k_updates first writes partialA.
  ushort* wsp = (ushort*)partialA;

  k_init<<<224, 256, 0, stream>>>(noise, mu, sigma, slots);
  k_wsplit<<<64, 256, 0, stream>>>(Wk, Wv, wsp);
  k_lnkv<<<4096, 256, 0, stream>>>(emb, wsp, bk, bv, lin_g, lin_b, keys, values);
  for (int it = 0; it < ITERS_; it++) {
    k_q<<<448, 128, 0, stream>>>(slots, Wq, bq, ls_g, ls_b, qbuf);
    k_logits<<<512, 256, 0, stream>>>(qbuf, keys, logits);
    k_softmax<<<448, 256, 0, stream>>>(logits);
    k_updates<<<512, 256, 0, stream>>>(logits, values, partialA);
    k_gruff<<<448, 128, 0, stream>>>(partialA, slots, Wih, Whh, bih, bhh,
                                     W1, b1, W2, b2, lff_g, lff_b);
  }
}

// Round 3
// 605.622 us; speedup vs baseline: 1.4764x; 1.3655x over previous
//
#include <hip/hip_runtime.h>
#include <math.h>

#define B_ 64
#define N_ 4096
#define D_ 128
#define S_ 7
#define H_ 256
#define ITERS_ 3
#define AP 132   // padded fp32 LDS row stride

__device__ __forceinline__ float dot4(float4 a, float4 b) {
  return a.x * b.x + a.y * b.y + a.z * b.z + a.w * b.w;
}
__device__ __forceinline__ float4 ld4(const float* p) {
  return *reinterpret_cast<const float4*>(p);
}

// ---------------- K0: slots = mu + sigma * noise ----------------
__global__ void k_init(const float* __restrict__ noise, const float* __restrict__ mu,
                       const float* __restrict__ sigma, float* __restrict__ slots) {
  int idx = blockIdx.x * 256 + threadIdx.x;  // 57344 total
  int d = idx & 127;
  slots[idx] = mu[d] + sigma[d] * noise[idx];
}

// ---------------- K1: lnbuf = LayerNorm(emb) (pure streaming, fp32) ----------------
// keys/values are NEVER materialized: logits use q'=q@Wk (tiny), updates use
// (attn@LN)@Wv^T (tiny epilogue in k_gruff). This removes the 16.7 GFLOP GEMM +
// 268MB of key/value writes entirely, and keeps the whole pipeline fp32.
__global__ __launch_bounds__(256) void k_ln(
    const float* __restrict__ emb, const float* __restrict__ lng, const float* __restrict__ lnb,
    float* __restrict__ lnbuf) {
  int t = threadIdx.x;
  long rowbase = (long)blockIdx.x * 64;
  int r = t >> 2;
  int io = (t & 3) * 32;
  const float* src = emb + (rowbase + r) * D_ + io;
  float* dst = lnbuf + (rowbase + r) * D_ + io;
  float4 xv[8];
  float sum = 0.f, sumsq = 0.f;
#pragma unroll
  for (int k = 0; k < 8; k++) {
    xv[k] = reinterpret_cast<const float4*>(src)[k];
    sum += xv[k].x + xv[k].y + xv[k].z + xv[k].w;
    sumsq += xv[k].x * xv[k].x + xv[k].y * xv[k].y + xv[k].z * xv[k].z + xv[k].w * xv[k].w;
  }
  sum += __shfl_xor(sum, 1, 4);   sum += __shfl_xor(sum, 2, 4);
  sumsq += __shfl_xor(sumsq, 1, 4); sumsq += __shfl_xor(sumsq, 2, 4);
  float mean = sum * (1.f / 128.f);
  float var = sumsq * (1.f / 128.f) - mean * mean;
  float rs = rsqrtf(var + 1e-5f);
#pragma unroll
  for (int k = 0; k < 8; k++) {
    float4 gv = reinterpret_cast<const float4*>(lng + io)[k];
    float4 bv4 = reinterpret_cast<const float4*>(lnb + io)[k];
    float4 o;
    o.x = (xv[k].x - mean) * rs * gv.x + bv4.x;
    o.y = (xv[k].y - mean) * rs * gv.y + bv4.y;
    o.z = (xv[k].z - mean) * rs * gv.z + bv4.z;
    o.w = (xv[k].w - mean) * rs * gv.w + bv4.w;
    reinterpret_cast<float4*>(dst)[k] = o;
  }
}

// ---------------- K2: q = LN(slots)@Wq^T + bq;  q' = q@Wk  ----------------
// q' absorbs Wk so logits = q'.LN^T. The q.bk term is a per-(b,s) constant ->
// cancels exactly in softmax, so it is dropped.
__global__ __launch_bounds__(128) void k_q(
    const float* __restrict__ slots, const float* __restrict__ Wq, const float* __restrict__ bq,
    const float* __restrict__ g, const float* __restrict__ b,
    const float* __restrict__ Wk, float* __restrict__ qp) {
  __shared__ __align__(16) float lns[AP];
  __shared__ __align__(16) float qs2[AP];
  __shared__ float red[4];
  int row = blockIdx.x;  // b*7+s
  int d = threadIdx.x;
  float x = slots[row * D_ + d];
  float s1 = x, s2 = x * x;
#pragma unroll
  for (int off = 32; off >= 1; off >>= 1) { s1 += __shfl_down(s1, off); s2 += __shfl_down(s2, off); }
  if ((d & 63) == 0) { red[(d >> 6) * 2] = s1; red[(d >> 6) * 2 + 1] = s2; }
  __syncthreads();
  float sum = red[0] + red[2], sumsq = red[1] + red[3];
  float mean = sum * (1.f / 128.f);
  float var = sumsq * (1.f / 128.f) - mean * mean;
  float rs = rsqrtf(var + 1e-5f);
  lns[d] = (x - mean) * rs * g[d] + b[d];
  __syncthreads();
  const float* w = Wq + d * D_;
  float acc = bq[d];
  for (int i4 = 0; i4 < D_; i4 += 4) acc += dot4(*reinterpret_cast<const float4*>(&lns[i4]), ld4(w + i4));
  qs2[d] = acc;
  __syncthreads();
  // q'[row][d] = sum_dd q[row][dd] * Wk[dd][d]  (Wk column access: coalesced across lanes)
  float qpa = 0.f;
#pragma unroll 4
  for (int dd = 0; dd < D_; dd++) qpa += qs2[dd] * Wk[dd * D_ + d];
  qp[row * D_ + d] = qpa;
}

// ---------------- K3a: logits[b][s][j] = q'[b,s,:] . lnbuf[b,j,:] ----------------
__global__ __launch_bounds__(256) void k_logits(
    const float* __restrict__ qpbuf, const float* __restrict__ lnbuf, float* __restrict__ logits) {
  __shared__ __align__(16) float qs[7 * AP];
  __shared__ __align__(16) float kt[64 * AP];
  __shared__ float red[28 * 64];  // [g*7+s][j]
  int t = threadIdx.x;
  int b = blockIdx.x >> 3, jc = blockIdx.x & 7;
  if (t < 224) {
    int s = t >> 5, i4 = (t & 31) * 4;
    *reinterpret_cast<float4*>(&qs[s * AP + i4]) =
        ld4(&qpbuf[(b * 7 + s) * D_ + i4]);
  }
  int j = t & 63, g = t >> 6, ib = g * 32;
  for (int sub = 0; sub < 8; sub++) {
    int j0 = jc * 512 + sub * 64;
#pragma unroll
    for (int u = 0; u < 8; u++) {
      int f = u * 256 + t;
      int row = f >> 5, i4 = (f & 31) * 4;
      *reinterpret_cast<float4*>(&kt[row * AP + i4]) =
          ld4(&lnbuf[((long)b * N_ + j0 + row) * D_ + i4]);
    }
    __syncthreads();
    float acc7[7];
#pragma unroll
    for (int s = 0; s < 7; s++) acc7[s] = 0.f;
#pragma unroll
    for (int st = 0; st < 8; st++) {
      float4 kv = *reinterpret_cast<const float4*>(&kt[j * AP + ib + st * 4]);
#pragma unroll
      for (int s = 0; s < 7; s++) {
        float4 qv = *reinterpret_cast<const float4*>(&qs[s * AP + ib + st * 4]);
        acc7[s] += dot4(kv, qv);
      }
    }
#pragma unroll
    for (int s = 0; s < 7; s++) red[(g * 7 + s) * 64 + j] = acc7[s];
    __syncthreads();
    for (int pp = t; pp < 448; pp += 256) {
      int s = pp >> 6, jj = pp & 63;
      float l = red[s * 64 + jj] + red[(7 + s) * 64 + jj] +
                red[(14 + s) * 64 + jj] + red[(21 + s) * 64 + jj];
      logits[(long)(b * 7 + s) * N_ + j0 + jj] = l;
    }
    __syncthreads();
  }
}

// ---------------- K3b: softmax over N, in place ----------------
// NOTE: reference's (softmax+1e-8)/renorm is a <=4.1e-5 relative perturbation -> skipped.
__global__ __launch_bounds__(256) void k_softmax(float* __restrict__ logits) {
  __shared__ float sm[4], ss[4];
  long base = (long)blockIdx.x * N_;
  int t = threadIdx.x;
  float4 v[4];
  float lmax = -1e30f;
#pragma unroll
  for (int p = 0; p < 4; p++) {
    v[p] = ld4(&logits[base + (p * 256 + t) * 4]);
    lmax = fmaxf(lmax, fmaxf(fmaxf(v[p].x, v[p].y), fmaxf(v[p].z, v[p].w)));
  }
#pragma unroll
  for (int off = 32; off >= 1; off >>= 1) lmax = fmaxf(lmax, __shfl_down(lmax, off));
  if ((t & 63) == 0) sm[t >> 6] = lmax;
  __syncthreads();
  float m = fmaxf(fmaxf(sm[0], sm[1]), fmaxf(sm[2], sm[3]));
  float lsum = 0.f;
#pragma unroll
  for (int p = 0; p < 4; p++) {
    v[p].x = __expf(v[p].x - m); v[p].y = __expf(v[p].y - m);
    v[p].z = __expf(v[p].z - m); v[p].w = __expf(v[p].w - m);
    lsum += v[p].x + v[p].y + v[p].z + v[p].w;
  }
#pragma unroll
  for (int off = 32; off >= 1; off >>= 1) lsum += __shfl_down(lsum, off);
  if ((t & 63) == 0) ss[t >> 6] = lsum;
  __syncthreads();
  float inv = 1.f / (ss[0] + ss[1] + ss[2] + ss[3]);
#pragma unroll
  for (int p = 0; p < 4; p++) {
    v[p].x *= inv; v[p].y *= inv; v[p].z *= inv; v[p].w *= inv;
    *reinterpret_cast<float4*>(&logits[base + (p * 256 + t) * 4]) = v[p];
  }
}

// ---------------- K3c: partialA[b][jc][s][d] = sum_{j in chunk} p[b,s,j] * lnbuf[b,j,d] ----------------
// (accumulates u' = attn @ LN; the @Wv^T + bv epilogue happens in k_gruff)
__global__ __launch_bounds__(256) void k_updates(
    const float* __restrict__ p, const float* __restrict__ lnbuf, float* __restrict__ partialA) {
  __shared__ __align__(16) float vt[64 * AP];  // reused as red[8][7][128] at the end
  __shared__ float pt[7 * 64];
  int t = threadIdx.x;
  int b = blockIdx.x >> 3, jc = blockIdx.x & 7;
  int d4 = (t & 31) * 4, jg = t >> 5;
  float acc[7][4];
#pragma unroll
  for (int s = 0; s < 7; s++)
#pragma unroll
    for (int c = 0; c < 4; c++) acc[s][c] = 0.f;

  for (int sub = 0; sub < 8; sub++) {
    int j0 = jc * 512 + sub * 64;
#pragma unroll
    for (int u = 0; u < 8; u++) {
      int f = u * 256 + t;
      int row = f >> 5, i4 = (f & 31) * 4;
      *reinterpret_cast<float4*>(&vt[row * AP + i4]) =
          ld4(&lnbuf[((long)b * N_ + j0 + row) * D_ + i4]);
    }
    for (int pp = t; pp < 448; pp += 256) {
      int s = pp >> 6, jj = pp & 63;
      pt[s * 64 + jj] = p[(long)(b * 7 + s) * N_ + j0 + jj];
    }
    __syncthreads();
#pragma unroll
    for (int jl = 0; jl < 8; jl++) {
      int jj = jg * 8 + jl;
      float4 vv = *reinterpret_cast<const float4*>(&vt[jj * AP + d4]);
#pragma unroll
      for (int s = 0; s < 7; s++) {
        float e = pt[s * 64 + jj];
        acc[s][0] += e * vv.x; acc[s][1] += e * vv.y;
        acc[s][2] += e * vv.z; acc[s][3] += e * vv.w;
      }
    }
    __syncthreads();
  }
  float* red = vt;
#pragma unroll
  for (int s = 0; s < 7; s++)
    *reinterpret_cast<float4*>(&red[(jg * 7 + s) * 128 + d4]) =
        make_float4(acc[s][0], acc[s][1], acc[s][2], acc[s][3]);
  __syncthreads();
  for (int pp = t; pp < 896; pp += 256) {
    int s = pp >> 7, d = pp & 127;
    float x = 0.f;
#pragma unroll
    for (int g = 0; g < 8; g++) x += red[(g * 7 + s) * 128 + d];
    partialA[((long)(b * 8 + jc) * 7 + s) * 128 + d] = x;
  }
}

// ---------------- K4: u'@Wv^T + bv -> updates; GRUCell + LN + FFN (+residual) ----------------
__global__ __launch_bounds__(128) void k_gruff(
    const float* __restrict__ partialA, float* __restrict__ slots,
    const float* __restrict__ Wv, const float* __restrict__ bv,
    const float* __restrict__ Wih, const float* __restrict__ Whh,
    const float* __restrict__ bih, const float* __restrict__ bhh,
    const float* __restrict__ W1, const float* __restrict__ b1,
    const float* __restrict__ W2, const float* __restrict__ b2,
    const float* __restrict__ gff, const float* __restrict__ bff) {
  __shared__ __align__(16) float us[AP];
  __shared__ __align__(16) float xs[AP];
  __shared__ __align__(16) float hs[AP];
  __shared__ __align__(16) float lns[AP];
  __shared__ __align__(16) float h1s[H_];
  __shared__ float red4[4];
  int blk = blockIdx.x;
  int b = blk / 7, s = blk % 7;
  int d = threadIdx.x;

  // u'[s][d] = combined attn@LN partials
  float up = 0.f;
#pragma unroll
  for (int jc = 0; jc < 8; jc++) up += partialA[((long)(b * 8 + jc) * 7 + s) * 128 + d];
  us[d] = up;
  __syncthreads();

  // updates[d] = u' . Wv[d,:] + bv[d]   (== (attn@values)[d] up to fp32 association)
  float x = bv[d];
  {
    const float* wvr = Wv + d * D_;
    for (int i4 = 0; i4 < D_; i4 += 4)
      x += dot4(*reinterpret_cast<const float4*>(&us[i4]), ld4(wvr + i4));
  }
  float h = slots[blk * D_ + d];
  xs[d] = x; hs[d] = h;
  __syncthreads();

  float gir = bih[d], giz = bih[128 + d], gin = bih[256 + d];
  float ghr = bhh[d], ghz = bhh[128 + d], ghn = bhh[256 + d];
  const float* wir = Wih + d * D_;
  const float* wiz = Wih + (128 + d) * D_;
  const float* win = Wih + (256 + d) * D_;
  const float* whr = Whh + d * D_;
  const float* whz = Whh + (128 + d) * D_;
  const float* whn = Whh + (256 + d) * D_;
  for (int i4 = 0; i4 < D_; i4 += 4) {
    float4 xv = *reinterpret_cast<const float4*>(&xs[i4]);
    float4 hv = *reinterpret_cast<const float4*>(&hs[i4]);
    gir += dot4(xv, ld4(wir + i4)); giz += dot4(xv, ld4(wiz + i4)); gin += dot4(xv, ld4(win + i4));
    ghr += dot4(hv, ld4(whr + i4)); ghz += dot4(hv, ld4(whz + i4)); ghn += dot4(hv, ld4(whn + i4));
  }
  float r = 1.f / (1.f + __expf(-(gir + ghr)));
  float z = 1.f / (1.f + __expf(-(giz + ghz)));
  float n = tanhf(gin + r * ghn);
  float ns = (1.f - z) * n + z * h;

  // LN over the new slot row
  float s1 = ns, s2 = ns * ns;
#pragma unroll
  for (int off = 32; off >= 1; off >>= 1) { s1 += __shfl_down(s1, off); s2 += __shfl_down(s2, off); }
  if ((d & 63) == 0) { red4[(d >> 6) * 2] = s1; red4[(d >> 6) * 2 + 1] = s2; }
  __syncthreads();
  float sum = red4[0] + red4[2], sumsq = red4[1] + red4[3];
  float mean = sum * (1.f / 128.f);
  float var = sumsq * (1.f / 128.f) - mean * mean;
  float rs = rsqrtf(var + 1e-5f);
  lns[d] = (ns - mean) * rs * gff[d] + bff[d];
  __syncthreads();

  float a0 = b1[d], a1 = b1[d + 128];
  const float* w1a = W1 + d * D_;
  const float* w1b = W1 + (128 + d) * D_;
  for (int i4 = 0; i4 < D_; i4 += 4) {
    float4 lv = *reinterpret_cast<const float4*>(&lns[i4]);
    a0 += dot4(lv, ld4(w1a + i4));
    a1 += dot4(lv, ld4(w1b + i4));
  }
  h1s[d] = fmaxf(a0, 0.f);
  h1s[d + 128] = fmaxf(a1, 0.f);
  __syncthreads();

  float f = b2[d];
  const float* w2r = W2 + d * H_;
  for (int h4 = 0; h4 < H_; h4 += 4)
    f += dot4(*reinterpret_cast<const float4*>(&h1s[h4]), ld4(w2r + h4));
  slots[blk * D_ + d] = ns + f;
}

extern "C" void kernel_launch(void* const* d_in, const int* in_sizes, int n_in,
                              void* d_out, int out_size, void* d_ws, size_t ws_size,
                              hipStream_t stream) {
  const float* emb   = (const float*)d_in[0];
  const float* noise = (const float*)d_in[1];
  const float* mu    = (const float*)d_in[2];
  const float* sigma = (const float*)d_in[3];
  const float* Wk = (const float*)d_in[4];  const float* bk = (const float*)d_in[5];
  const float* Wq = (const float*)d_in[6];  const float* bq = (const float*)d_in[7];
  const float* Wv = (const float*)d_in[8];  const float* bv = (const float*)d_in[9];
  const float* Wih = (const float*)d_in[10]; const float* Whh = (const float*)d_in[11];
  const float* bih = (const float*)d_in[12]; const float* bhh = (const float*)d_in[13];
  const float* W1 = (const float*)d_in[14];  const float* b1 = (const float*)d_in[15];
  const float* W2 = (const float*)d_in[16];  const float* b2 = (const float*)d_in[17];
  const float* lin_g = (const float*)d_in[18]; const float* lin_b = (const float*)d_in[19];
  const float* ls_g  = (const float*)d_in[20]; const float* ls_b  = (const float*)d_in[21];
  const float* lff_g = (const float*)d_in[22]; const float* lff_b = (const float*)d_in[23];
  (void)bk;  // q.bk is softmax-invariant (cancels exactly); not needed

  float* slots = (float*)d_out;  // [B,S,D] lives in d_out, updated in place
  float* lnbuf    = (float*)d_ws;                       // 33,554,432 f  (LN(emb))
  float* qp       = lnbuf + (size_t)B_ * N_ * D_;       // 57,344 f     (q' = q@Wk)
  float* logits   = qp + (size_t)B_ * S_ * D_;          // 1,835,008 f
  float* partialA = logits + (size_t)B_ * S_ * N_;      // 458,752 f    (u' partials)

  k_init<<<224, 256, 0, stream>>>(noise, mu, sigma, slots);
  k_ln<<<4096, 256, 0, stream>>>(emb, lin_g, lin_b, lnbuf);
  for (int it = 0; it < ITERS_; it++) {
    k_q<<<448, 128, 0, stream>>>(slots, Wq, bq, ls_g, ls_b, Wk, qp);
    k_logits<<<512, 256, 0, stream>>>(qp, lnbuf, logits);
    k_softmax<<<448, 256, 0, stream>>>(logits);
    k_updates<<<512, 256, 0, stream>>>(logits, lnbuf, partialA);
    k_gruff<<<448, 128, 0, stream>>>(partialA, slots, Wv, bv, Wih, Whh, bih, bhh,
                                     W1, b1, W2, b2, lff_g, lff_b);
  }
}

// Round 4
// 557.494 us; speedup vs baseline: 1.6038x; 1.0863x over previous
//
#include <hip/hip_runtime.h>
#include <math.h>

#define B_ 64
#define N_ 4096
#define D_ 128
#define S_ 7
#define H_ 256
#define ITERS_ 3
#define AP 132   // padded fp32 LDS row stride

__device__ __forceinline__ float dot4(float4 a, float4 b) {
  return a.x * b.x + a.y * b.y + a.z * b.z + a.w * b.w;
}
__device__ __forceinline__ float4 ld4(const float* p) {
  return *reinterpret_cast<const float4*>(p);
}

// ---------------- K0: slots = mu + sigma * noise ----------------
__global__ void k_init(const float* __restrict__ noise, const float* __restrict__ mu,
                       const float* __restrict__ sigma, float* __restrict__ slots) {
  int idx = blockIdx.x * 256 + threadIdx.x;  // 57344 total
  int d = idx & 127;
  slots[idx] = mu[d] + sigma[d] * noise[idx];
}

// ---------------- K1: lnbuf = LayerNorm(emb) (pure streaming, fp32) ----------------
__global__ __launch_bounds__(256) void k_ln(
    const float* __restrict__ emb, const float* __restrict__ lng, const float* __restrict__ lnb,
    float* __restrict__ lnbuf) {
  int t = threadIdx.x;
  long rowbase = (long)blockIdx.x * 64;
  int r = t >> 2;
  int io = (t & 3) * 32;
  const float* src = emb + (rowbase + r) * D_ + io;
  float* dst = lnbuf + (rowbase + r) * D_ + io;
  float4 xv[8];
  float sum = 0.f, sumsq = 0.f;
#pragma unroll
  for (int k = 0; k < 8; k++) {
    xv[k] = reinterpret_cast<const float4*>(src)[k];
    sum += xv[k].x + xv[k].y + xv[k].z + xv[k].w;
    sumsq += xv[k].x * xv[k].x + xv[k].y * xv[k].y + xv[k].z * xv[k].z + xv[k].w * xv[k].w;
  }
  sum += __shfl_xor(sum, 1, 4);   sum += __shfl_xor(sum, 2, 4);
  sumsq += __shfl_xor(sumsq, 1, 4); sumsq += __shfl_xor(sumsq, 2, 4);
  float mean = sum * (1.f / 128.f);
  float var = sumsq * (1.f / 128.f) - mean * mean;
  float rs = rsqrtf(var + 1e-5f);
#pragma unroll
  for (int k = 0; k < 8; k++) {
    float4 gv = reinterpret_cast<const float4*>(lng + io)[k];
    float4 bv4 = reinterpret_cast<const float4*>(lnb + io)[k];
    float4 o;
    o.x = (xv[k].x - mean) * rs * gv.x + bv4.x;
    o.y = (xv[k].y - mean) * rs * gv.y + bv4.y;
    o.z = (xv[k].z - mean) * rs * gv.z + bv4.z;
    o.w = (xv[k].w - mean) * rs * gv.w + bv4.w;
    reinterpret_cast<float4*>(dst)[k] = o;
  }
}

// ---------------- K2: q = LN(slots)@Wq^T + bq;  q' = q@Wk  ----------------
// q' absorbs Wk so logits = q'.LN^T. The q.bk term is a per-(b,s) constant ->
// cancels exactly in softmax, so it is dropped.
__global__ __launch_bounds__(128) void k_q(
    const float* __restrict__ slots, const float* __restrict__ Wq, const float* __restrict__ bq,
    const float* __restrict__ g, const float* __restrict__ b,
    const float* __restrict__ Wk, float* __restrict__ qp) {
  __shared__ __align__(16) float lns[AP];
  __shared__ __align__(16) float qs2[AP];
  __shared__ float red[4];
  int row = blockIdx.x;  // b*7+s
  int d = threadIdx.x;
  float x = slots[row * D_ + d];
  float s1 = x, s2 = x * x;
#pragma unroll
  for (int off = 32; off >= 1; off >>= 1) { s1 += __shfl_down(s1, off); s2 += __shfl_down(s2, off); }
  if ((d & 63) == 0) { red[(d >> 6) * 2] = s1; red[(d >> 6) * 2 + 1] = s2; }
  __syncthreads();
  float sum = red[0] + red[2], sumsq = red[1] + red[3];
  float mean = sum * (1.f / 128.f);
  float var = sumsq * (1.f / 128.f) - mean * mean;
  float rs = rsqrtf(var + 1e-5f);
  lns[d] = (x - mean) * rs * g[d] + b[d];
  __syncthreads();
  const float* w = Wq + d * D_;
  float acc = bq[d];
  for (int i4 = 0; i4 < D_; i4 += 4) acc += dot4(*reinterpret_cast<const float4*>(&lns[i4]), ld4(w + i4));
  qs2[d] = acc;
  __syncthreads();
  // q'[row][d] = sum_dd q[row][dd] * Wk[dd][d]  (coalesced across lanes)
  float qpa = 0.f;
#pragma unroll 4
  for (int dd = 0; dd < D_; dd++) qpa += qs2[dd] * Wk[dd * D_ + d];
  qp[row * D_ + d] = qpa;
}

// ---------------- K3: fused flash attention over one j-chunk of 512 ----------------
// Per (b, jc): single pass over the 512-row LN tile, used BOTH as K (logits)
// and V (update). Online softmax: running chunk max sm[s] / sum ssum[s];
// acc holds sum_j exp(l_j - sm) * LN[j]. Cross-chunk combine in k_gruff.
// Logits use the bit-identical summation tree as the previous k_logits.
__global__ __launch_bounds__(256) void k_attn(
    const float* __restrict__ qpbuf, const float* __restrict__ lnbuf,
    float* __restrict__ partialA, float* __restrict__ partialM, float* __restrict__ partialS) {
  __shared__ __align__(16) float qs[7 * AP];
  __shared__ __align__(16) float vt[64 * AP];   // LN tile (K and V); reused as red-f at end
  __shared__ float red[28 * 64];                // logit partials [g*7+s][j]
  __shared__ float pt[7 * 64];                  // combined logits -> exp weights
  __shared__ float sm[7], ssum[7], tmax[7];
  int t = threadIdx.x;
  int b = blockIdx.x >> 3, jc = blockIdx.x & 7;

  if (t < 224) {
    int s = t >> 5, i4 = (t & 31) * 4;
    *reinterpret_cast<float4*>(&qs[s * AP + i4]) = ld4(&qpbuf[(b * 7 + s) * D_ + i4]);
  }
  if (t < 7) { sm[t] = -1e30f; ssum[t] = 0.f; }

  int j = t & 63, g = t >> 6, ib = g * 32;      // logits roles
  int d4 = (t & 31) * 4, jg = t >> 5;           // update roles
  float acc[7][4];
#pragma unroll
  for (int s = 0; s < 7; s++)
#pragma unroll
    for (int c = 0; c < 4; c++) acc[s][c] = 0.f;
  __syncthreads();

  for (int sub = 0; sub < 8; sub++) {
    int j0 = jc * 512 + sub * 64;
    // stage LN tile
#pragma unroll
    for (int u = 0; u < 8; u++) {
      int f = u * 256 + t;
      int row = f >> 5, i4 = (f & 31) * 4;
      *reinterpret_cast<float4*>(&vt[row * AP + i4]) =
          ld4(&lnbuf[((long)b * N_ + j0 + row) * D_ + i4]);
    }
    __syncthreads();

    // logits partial dots (same tree as old k_logits)
    float acc7[7];
#pragma unroll
    for (int s = 0; s < 7; s++) acc7[s] = 0.f;
#pragma unroll
    for (int st = 0; st < 8; st++) {
      float4 kv = *reinterpret_cast<const float4*>(&vt[j * AP + ib + st * 4]);
#pragma unroll
      for (int s = 0; s < 7; s++) {
        float4 qv = *reinterpret_cast<const float4*>(&qs[s * AP + ib + st * 4]);
        acc7[s] += dot4(kv, qv);
      }
    }
#pragma unroll
    for (int s = 0; s < 7; s++) red[(g * 7 + s) * 64 + j] = acc7[s];
    __syncthreads();

    // combine 4 partials -> raw logits in pt (identical sum order to before)
    for (int pp = t; pp < 448; pp += 256) {
      int s = pp >> 6, jj = pp & 63;
      pt[pp] = red[s * 64 + jj] + red[(7 + s) * 64 + jj] +
               red[(14 + s) * 64 + jj] + red[(21 + s) * 64 + jj];
    }
    __syncthreads();

    // tile max per s (32-thread groups)
    if (t < 224) {
      int s = t >> 5, i = t & 31;
      float m = fmaxf(pt[s * 64 + i], pt[s * 64 + 32 + i]);
#pragma unroll
      for (int off = 16; off >= 1; off >>= 1) m = fmaxf(m, __shfl_down(m, off, 32));
      if ((t & 31) == 0) tmax[s] = m;
    }
    __syncthreads();

    // rescale acc by exp(m_old - m_new); s is compile-time here (no reg-indexed array)
#pragma unroll
    for (int s = 0; s < 7; s++) {
      float mnew = fmaxf(sm[s], tmax[s]);
      float scl = __expf(sm[s] - mnew);
#pragma unroll
      for (int c = 0; c < 4; c++) acc[s][c] *= scl;
    }
    // exponentiate logits (mnew recomputed from LDS; sm not yet updated)
    for (int pp = t; pp < 448; pp += 256) {
      int s = pp >> 6;
      float mnew = fmaxf(sm[s], tmax[s]);
      pt[pp] = __expf(pt[pp] - mnew);
    }
    __syncthreads();

    // chunk sum + state update (lane 0 of each 32-group owns s)
    if (t < 224) {
      int s = t >> 5, i = t & 31;
      float ssub = pt[s * 64 + i] + pt[s * 64 + 32 + i];
#pragma unroll
      for (int off = 16; off >= 1; off >>= 1) ssub += __shfl_down(ssub, off, 32);
      if ((t & 31) == 0) {
        float mnew = fmaxf(sm[s], tmax[s]);
        float scl = __expf(sm[s] - mnew);
        ssum[s] = ssum[s] * scl + ssub;
        sm[s] = mnew;
      }
    }

    // V-accumulate (unnormalized, scaled to current sm)
#pragma unroll
    for (int jl = 0; jl < 8; jl++) {
      int jj = jg * 8 + jl;
      float4 vv = *reinterpret_cast<const float4*>(&vt[jj * AP + d4]);
#pragma unroll
      for (int s = 0; s < 7; s++) {
        float e = pt[s * 64 + jj];
        acc[s][0] += e * vv.x; acc[s][1] += e * vv.y;
        acc[s][2] += e * vv.z; acc[s][3] += e * vv.w;
      }
    }
    __syncthreads();  // protects vt/pt/red restage + sm/ssum visibility
  }

  // cross-jg reduction (reuse vt)
  float* redf = vt;
#pragma unroll
  for (int s = 0; s < 7; s++)
    *reinterpret_cast<float4*>(&redf[(jg * 7 + s) * 128 + d4]) =
        make_float4(acc[s][0], acc[s][1], acc[s][2], acc[s][3]);
  __syncthreads();
  for (int pp = t; pp < 896; pp += 256) {
    int s = pp >> 7, d = pp & 127;
    float x = 0.f;
#pragma unroll
    for (int g2 = 0; g2 < 8; g2++) x += redf[(g2 * 7 + s) * 128 + d];
    partialA[((long)(b * 8 + jc) * 7 + s) * 128 + d] = x;
  }
  if (t < 7) {
    partialM[(b * 8 + jc) * 7 + t] = sm[t];
    partialS[(b * 8 + jc) * 7 + t] = ssum[t];
  }
}

// ---------------- K4: flash combine + u'@Wv^T + bv; GRUCell + LN + FFN ----------------
__global__ __launch_bounds__(128) void k_gruff(
    const float* __restrict__ partialA, const float* __restrict__ partialM,
    const float* __restrict__ partialS, float* __restrict__ slots,
    const float* __restrict__ Wv, const float* __restrict__ bv,
    const float* __restrict__ Wih, const float* __restrict__ Whh,
    const float* __restrict__ bih, const float* __restrict__ bhh,
    const float* __restrict__ W1, const float* __restrict__ b1,
    const float* __restrict__ W2, const float* __restrict__ b2,
    const float* __restrict__ gff, const float* __restrict__ bff) {
  __shared__ __align__(16) float us[AP];
  __shared__ __align__(16) float xs[AP];
  __shared__ __align__(16) float hs[AP];
  __shared__ __align__(16) float lns[AP];
  __shared__ __align__(16) float h1s[H_];
  __shared__ float red4[4];
  int blk = blockIdx.x;
  int b = blk / 7, s = blk % 7;
  int d = threadIdx.x;

  // flash combine over the 8 j-chunks (redundant per-thread scalars; all cached)
  float mg = -1e30f;
#pragma unroll
  for (int c = 0; c < 8; c++) mg = fmaxf(mg, partialM[(b * 8 + c) * 7 + s]);
  float denom = 0.f, up = 0.f;
#pragma unroll
  for (int c = 0; c < 8; c++) {
    float w = __expf(partialM[(b * 8 + c) * 7 + s] - mg);
    denom += w * partialS[(b * 8 + c) * 7 + s];
    up += w * partialA[((long)(b * 8 + c) * 7 + s) * 128 + d];
  }
  us[d] = up / denom;
  __syncthreads();

  // updates[d] = u' . Wv[d,:] + bv[d]
  float x = bv[d];
  {
    const float* wvr = Wv + d * D_;
    for (int i4 = 0; i4 < D_; i4 += 4)
      x += dot4(*reinterpret_cast<const float4*>(&us[i4]), ld4(wvr + i4));
  }
  float h = slots[blk * D_ + d];
  xs[d] = x; hs[d] = h;
  __syncthreads();

  float gir = bih[d], giz = bih[128 + d], gin = bih[256 + d];
  float ghr = bhh[d], ghz = bhh[128 + d], ghn = bhh[256 + d];
  const float* wir = Wih + d * D_;
  const float* wiz = Wih + (128 + d) * D_;
  const float* win = Wih + (256 + d) * D_;
  const float* whr = Whh + d * D_;
  const float* whz = Whh + (128 + d) * D_;
  const float* whn = Whh + (256 + d) * D_;
  for (int i4 = 0; i4 < D_; i4 += 4) {
    float4 xv = *reinterpret_cast<const float4*>(&xs[i4]);
    float4 hv = *reinterpret_cast<const float4*>(&hs[i4]);
    gir += dot4(xv, ld4(wir + i4)); giz += dot4(xv, ld4(wiz + i4)); gin += dot4(xv, ld4(win + i4));
    ghr += dot4(hv, ld4(whr + i4)); ghz += dot4(hv, ld4(whz + i4)); ghn += dot4(hv, ld4(whn + i4));
  }
  float r = 1.f / (1.f + __expf(-(gir + ghr)));
  float z = 1.f / (1.f + __expf(-(giz + ghz)));
  float n = tanhf(gin + r * ghn);
  float ns = (1.f - z) * n + z * h;

  // LN over the new slot row
  float s1 = ns, s2 = ns * ns;
#pragma unroll
  for (int off = 32; off >= 1; off >>= 1) { s1 += __shfl_down(s1, off); s2 += __shfl_down(s2, off); }
  if ((d & 63) == 0) { red4[(d >> 6) * 2] = s1; red4[(d >> 6) * 2 + 1] = s2; }
  __syncthreads();
  float sum = red4[0] + red4[2], sumsq = red4[1] + red4[3];
  float mean = sum * (1.f / 128.f);
  float var = sumsq * (1.f / 128.f) - mean * mean;
  float rs = rsqrtf(var + 1e-5f);
  lns[d] = (ns - mean) * rs * gff[d] + bff[d];
  __syncthreads();

  float a0 = b1[d], a1 = b1[d + 128];
  const float* w1a = W1 + d * D_;
  const float* w1b = W1 + (128 + d) * D_;
  for (int i4 = 0; i4 < D_; i4 += 4) {
    float4 lv = *reinterpret_cast<const float4*>(&lns[i4]);
    a0 += dot4(lv, ld4(w1a + i4));
    a1 += dot4(lv, ld4(w1b + i4));
  }
  h1s[d] = fmaxf(a0, 0.f);
  h1s[d + 128] = fmaxf(a1, 0.f);
  __syncthreads();

  float f = b2[d];
  const float* w2r = W2 + d * H_;
  for (int h4 = 0; h4 < H_; h4 += 4)
    f += dot4(*reinterpret_cast<const float4*>(&h1s[h4]), ld4(w2r + h4));
  slots[blk * D_ + d] = ns + f;
}

extern "C" void kernel_launch(void* const* d_in, const int* in_sizes, int n_in,
                              void* d_out, int out_size, void* d_ws, size_t ws_size,
                              hipStream_t stream) {
  const float* emb   = (const float*)d_in[0];
  const float* noise = (const float*)d_in[1];
  const float* mu    = (const float*)d_in[2];
  const float* sigma = (const float*)d_in[3];
  const float* Wk = (const float*)d_in[4];  const float* bk = (const float*)d_in[5];
  const float* Wq = (const float*)d_in[6];  const float* bq = (const float*)d_in[7];
  const float* Wv = (const float*)d_in[8];  const float* bv = (const float*)d_in[9];
  const float* Wih = (const float*)d_in[10]; const float* Whh = (const float*)d_in[11];
  const float* bih = (const float*)d_in[12]; const float* bhh = (const float*)d_in[13];
  const float* W1 = (const float*)d_in[14];  const float* b1 = (const float*)d_in[15];
  const float* W2 = (const float*)d_in[16];  const float* b2 = (const float*)d_in[17];
  const float* lin_g = (const float*)d_in[18]; const float* lin_b = (const float*)d_in[19];
  const float* ls_g  = (const float*)d_in[20]; const float* ls_b  = (const float*)d_in[21];
  const float* lff_g = (const float*)d_in[22]; const float* lff_b = (const float*)d_in[23];
  (void)bk;  // q.bk is softmax-invariant (cancels exactly)

  float* slots = (float*)d_out;  // [B,S,D] in d_out, updated in place
  float* lnbuf    = (float*)d_ws;                       // 33,554,432 f  (LN(emb))
  float* qp       = lnbuf + (size_t)B_ * N_ * D_;       // 57,344 f     (q' = q@Wk)
  float* partialA = qp + (size_t)B_ * S_ * D_;          // 458,752 f    (unnormalized u chunks)
  float* partialM = partialA + (size_t)B_ * 8 * S_ * D_; // 3,584 f     (chunk max)
  float* partialS = partialM + (size_t)B_ * 8 * S_;      // 3,584 f     (chunk sumexp)

  k_init<<<224, 256, 0, stream>>>(noise, mu, sigma, slots);
  k_ln<<<4096, 256, 0, stream>>>(emb, lin_g, lin_b, lnbuf);
  for (int it = 0; it < ITERS_; it++) {
    k_q<<<448, 128, 0, stream>>>(slots, Wq, bq, ls_g, ls_b, Wk, qp);
    k_attn<<<512, 256, 0, stream>>>(qp, lnbuf, partialA, partialM, partialS);
    k_gruff<<<448, 128, 0, stream>>>(partialA, partialM, partialS, slots, Wv, bv,
                                     Wih, Whh, bih, bhh, W1, b1, W2, b2, lff_g, lff_b);
  }
}

// Round 5
// 545.453 us; speedup vs baseline: 1.6392x; 1.0221x over previous
//
#include <hip/hip_runtime.h>
#include <math.h>

#define B_ 64
#define N_ 4096
#define D_ 128
#define S_ 7
#define H_ 256
#define ITERS_ 3
#define AP 132      // padded fp32 LDS row stride
#define NCHUNK 16   // j-chunks per batch (256 rows each)

__device__ __forceinline__ float dot4(float4 a, float4 b) {
  return a.x * b.x + a.y * b.y + a.z * b.z + a.w * b.w;
}
__device__ __forceinline__ float4 ld4(const float* p) {
  return *reinterpret_cast<const float4*>(p);
}

// ---------------- K0: slots = mu + sigma * noise ----------------
__global__ void k_init(const float* __restrict__ noise, const float* __restrict__ mu,
                       const float* __restrict__ sigma, float* __restrict__ slots) {
  int idx = blockIdx.x * 256 + threadIdx.x;  // 57344 total
  int d = idx & 127;
  slots[idx] = mu[d] + sigma[d] * noise[idx];
}

// ---------------- K2: q = LN(slots)@Wq^T + bq;  q' = q@Wk  ----------------
// q' absorbs Wk so logits = q'.LN^T. The q.bk term is a per-(b,s) constant ->
// cancels exactly in softmax, so it is dropped.
__global__ __launch_bounds__(128) void k_q(
    const float* __restrict__ slots, const float* __restrict__ Wq, const float* __restrict__ bq,
    const float* __restrict__ g, const float* __restrict__ b,
    const float* __restrict__ Wk, float* __restrict__ qp) {
  __shared__ __align__(16) float lns[AP];
  __shared__ __align__(16) float qs2[AP];
  __shared__ float red[4];
  int row = blockIdx.x;  // b*7+s
  int d = threadIdx.x;
  float x = slots[row * D_ + d];
  float s1 = x, s2 = x * x;
#pragma unroll
  for (int off = 32; off >= 1; off >>= 1) { s1 += __shfl_down(s1, off); s2 += __shfl_down(s2, off); }
  if ((d & 63) == 0) { red[(d >> 6) * 2] = s1; red[(d >> 6) * 2 + 1] = s2; }
  __syncthreads();
  float sum = red[0] + red[2], sumsq = red[1] + red[3];
  float mean = sum * (1.f / 128.f);
  float var = sumsq * (1.f / 128.f) - mean * mean;
  float rs = rsqrtf(var + 1e-5f);
  lns[d] = (x - mean) * rs * g[d] + b[d];
  __syncthreads();
  const float* w = Wq + d * D_;
  float acc = bq[d];
  for (int i4 = 0; i4 < D_; i4 += 4) acc += dot4(*reinterpret_cast<const float4*>(&lns[i4]), ld4(w + i4));
  qs2[d] = acc;
  __syncthreads();
  // q'[row][d] = sum_dd q[row][dd] * Wk[dd][d]  (coalesced across lanes)
  float qpa = 0.f;
#pragma unroll 4
  for (int dd = 0; dd < D_; dd++) qpa += qs2[dd] * Wk[dd * D_ + d];
  qp[row * D_ + d] = qpa;
}

// ---------------- K3: fused LN + flash attention over one j-chunk of 256 ----------------
// LN(emb) is computed on the fly while staging each 64-row tile into LDS (the
// tile serves as both K and V). Online softmax per chunk; combine in k_gruff.
// Logits keep the bit-identical summation tree of the previous version.
__global__ __launch_bounds__(256) void k_attn(
    const float* __restrict__ qpbuf, const float* __restrict__ emb,
    const float* __restrict__ lng, const float* __restrict__ lnb,
    float* __restrict__ partialA, float* __restrict__ partialM, float* __restrict__ partialS) {
  __shared__ __align__(16) float qs[7 * AP];
  __shared__ __align__(16) float vt[64 * AP];   // LN tile (K and V); reused as redf at end
  __shared__ float red[28 * 64];                // logit partials [g*7+s][j]
  __shared__ float pt[7 * 64];                  // combined logits -> exp weights
  __shared__ float sm[7], ssum[7], tmax[7];
  int t = threadIdx.x;
  int b = blockIdx.x >> 4, jc = blockIdx.x & (NCHUNK - 1);

  if (t < 224) {
    int s = t >> 5, i4 = (t & 31) * 4;
    *reinterpret_cast<float4*>(&qs[s * AP + i4]) = ld4(&qpbuf[(b * 7 + s) * D_ + i4]);
  }
  if (t < 7) { sm[t] = -1e30f; ssum[t] = 0.f; }

  int j = t & 63, g = t >> 6, ib = g * 32;      // logits roles
  int d4 = (t & 31) * 4, jg = t >> 5;           // update roles
  // LN staging constants (per-thread column is fixed across rows/subs)
  int ln_i4 = (t & 31) * 4;
  int ln_r8 = t >> 5;                           // row offset within an 8-row group
  float4 gv = ld4(&lng[ln_i4]);
  float4 bv4 = ld4(&lnb[ln_i4]);

  float acc[7][4];
#pragma unroll
  for (int s = 0; s < 7; s++)
#pragma unroll
    for (int c = 0; c < 4; c++) acc[s][c] = 0.f;
  __syncthreads();

  for (int sub = 0; sub < 4; sub++) {
    int j0 = jc * 256 + sub * 64;
    // stage + LN: 32 contiguous half-wave threads own one row
#pragma unroll
    for (int u = 0; u < 8; u++) {
      int row = u * 8 + ln_r8;
      float4 x = ld4(&emb[((long)b * N_ + j0 + row) * D_ + ln_i4]);
      float s1 = x.x + x.y + x.z + x.w;
      float s2 = dot4(x, x);
#pragma unroll
      for (int off = 16; off >= 1; off >>= 1) {
        s1 += __shfl_xor(s1, off, 32);
        s2 += __shfl_xor(s2, off, 32);
      }
      float mean = s1 * (1.f / 128.f);
      float var = s2 * (1.f / 128.f) - mean * mean;
      float rs = rsqrtf(var + 1e-5f);
      float4 o;
      o.x = (x.x - mean) * rs * gv.x + bv4.x;
      o.y = (x.y - mean) * rs * gv.y + bv4.y;
      o.z = (x.z - mean) * rs * gv.z + bv4.z;
      o.w = (x.w - mean) * rs * gv.w + bv4.w;
      *reinterpret_cast<float4*>(&vt[row * AP + ln_i4]) = o;
    }
    __syncthreads();

    // logits partial dots (same tree as before)
    float acc7[7];
#pragma unroll
    for (int s = 0; s < 7; s++) acc7[s] = 0.f;
#pragma unroll
    for (int st = 0; st < 8; st++) {
      float4 kv = *reinterpret_cast<const float4*>(&vt[j * AP + ib + st * 4]);
#pragma unroll
      for (int s = 0; s < 7; s++) {
        float4 qv = *reinterpret_cast<const float4*>(&qs[s * AP + ib + st * 4]);
        acc7[s] += dot4(kv, qv);
      }
    }
#pragma unroll
    for (int s = 0; s < 7; s++) red[(g * 7 + s) * 64 + j] = acc7[s];
    __syncthreads();

    // combine 4 partials -> raw logits in pt (identical sum order)
    for (int pp = t; pp < 448; pp += 256) {
      int s = pp >> 6, jj = pp & 63;
      pt[pp] = red[s * 64 + jj] + red[(7 + s) * 64 + jj] +
               red[(14 + s) * 64 + jj] + red[(21 + s) * 64 + jj];
    }
    __syncthreads();

    // tile max per s (32-thread groups)
    if (t < 224) {
      int s = t >> 5, i = t & 31;
      float m = fmaxf(pt[s * 64 + i], pt[s * 64 + 32 + i]);
#pragma unroll
      for (int off = 16; off >= 1; off >>= 1) m = fmaxf(m, __shfl_down(m, off, 32));
      if ((t & 31) == 0) tmax[s] = m;
    }
    __syncthreads();

    // rescale acc by exp(m_old - m_new)
#pragma unroll
    for (int s = 0; s < 7; s++) {
      float mnew = fmaxf(sm[s], tmax[s]);
      float scl = __expf(sm[s] - mnew);
#pragma unroll
      for (int c = 0; c < 4; c++) acc[s][c] *= scl;
    }
    // exponentiate logits (mnew recomputed from LDS; sm not yet updated)
    for (int pp = t; pp < 448; pp += 256) {
      int s = pp >> 6;
      float mnew = fmaxf(sm[s], tmax[s]);
      pt[pp] = __expf(pt[pp] - mnew);
    }
    __syncthreads();

    // chunk sum + state update
    if (t < 224) {
      int s = t >> 5, i = t & 31;
      float ssub = pt[s * 64 + i] + pt[s * 64 + 32 + i];
#pragma unroll
      for (int off = 16; off >= 1; off >>= 1) ssub += __shfl_down(ssub, off, 32);
      if ((t & 31) == 0) {
        float mnew = fmaxf(sm[s], tmax[s]);
        float scl = __expf(sm[s] - mnew);
        ssum[s] = ssum[s] * scl + ssub;
        sm[s] = mnew;
      }
    }

    // V-accumulate (unnormalized, scaled to current sm)
#pragma unroll
    for (int jl = 0; jl < 8; jl++) {
      int jj = jg * 8 + jl;
      float4 vv = *reinterpret_cast<const float4*>(&vt[jj * AP + d4]);
#pragma unroll
      for (int s = 0; s < 7; s++) {
        float e = pt[s * 64 + jj];
        acc[s][0] += e * vv.x; acc[s][1] += e * vv.y;
        acc[s][2] += e * vv.z; acc[s][3] += e * vv.w;
      }
    }
    __syncthreads();  // protects vt/pt/red restage + sm/ssum visibility
  }

  // cross-jg reduction (reuse vt)
  float* redf = vt;
#pragma unroll
  for (int s = 0; s < 7; s++)
    *reinterpret_cast<float4*>(&redf[(jg * 7 + s) * 128 + d4]) =
        make_float4(acc[s][0], acc[s][1], acc[s][2], acc[s][3]);
  __syncthreads();
  for (int pp = t; pp < 896; pp += 256) {
    int s = pp >> 7, d = pp & 127;
    float x = 0.f;
#pragma unroll
    for (int g2 = 0; g2 < 8; g2++) x += redf[(g2 * 7 + s) * 128 + d];
    partialA[((long)(b * NCHUNK + jc) * 7 + s) * 128 + d] = x;
  }
  if (t < 7) {
    partialM[(b * NCHUNK + jc) * 7 + t] = sm[t];
    partialS[(b * NCHUNK + jc) * 7 + t] = ssum[t];
  }
}

// ---------------- K4: flash combine + u'@Wv^T + bv; GRUCell + LN + FFN ----------------
__global__ __launch_bounds__(128) void k_gruff(
    const float* __restrict__ partialA, const float* __restrict__ partialM,
    const float* __restrict__ partialS, float* __restrict__ slots,
    const float* __restrict__ Wv, const float* __restrict__ bv,
    const float* __restrict__ Wih, const float* __restrict__ Whh,
    const float* __restrict__ bih, const float* __restrict__ bhh,
    const float* __restrict__ W1, const float* __restrict__ b1,
    const float* __restrict__ W2, const float* __restrict__ b2,
    const float* __restrict__ gff, const float* __restrict__ bff) {
  __shared__ __align__(16) float us[AP];
  __shared__ __align__(16) float xs[AP];
  __shared__ __align__(16) float hs[AP];
  __shared__ __align__(16) float lns[AP];
  __shared__ __align__(16) float h1s[H_];
  __shared__ float red4[4];
  int blk = blockIdx.x;
  int b = blk / 7, s = blk % 7;
  int d = threadIdx.x;

  // flash combine over the NCHUNK j-chunks
  float mg = -1e30f;
#pragma unroll
  for (int c = 0; c < NCHUNK; c++) mg = fmaxf(mg, partialM[(b * NCHUNK + c) * 7 + s]);
  float denom = 0.f, up = 0.f;
#pragma unroll
  for (int c = 0; c < NCHUNK; c++) {
    float w = __expf(partialM[(b * NCHUNK + c) * 7 + s] - mg);
    denom += w * partialS[(b * NCHUNK + c) * 7 + s];
    up += w * partialA[((long)(b * NCHUNK + c) * 7 + s) * 128 + d];
  }
  us[d] = up / denom;
  __syncthreads();

  // updates[d] = u' . Wv[d,:] + bv[d]
  float x = bv[d];
  {
    const float* wvr = Wv + d * D_;
    for (int i4 = 0; i4 < D_; i4 += 4)
      x += dot4(*reinterpret_cast<const float4*>(&us[i4]), ld4(wvr + i4));
  }
  float h = slots[blk * D_ + d];
  xs[d] = x; hs[d] = h;
  __syncthreads();

  float gir = bih[d], giz = bih[128 + d], gin = bih[256 + d];
  float ghr = bhh[d], ghz = bhh[128 + d], ghn = bhh[256 + d];
  const float* wir = Wih + d * D_;
  const float* wiz = Wih + (128 + d) * D_;
  const float* win = Wih + (256 + d) * D_;
  const float* whr = Whh + d * D_;
  const float* whz = Whh + (128 + d) * D_;
  const float* whn = Whh + (256 + d) * D_;
  for (int i4 = 0; i4 < D_; i4 += 4) {
    float4 xv = *reinterpret_cast<const float4*>(&xs[i4]);
    float4 hv = *reinterpret_cast<const float4*>(&hs[i4]);
    gir += dot4(xv, ld4(wir + i4)); giz += dot4(xv, ld4(wiz + i4)); gin += dot4(xv, ld4(win + i4));
    ghr += dot4(hv, ld4(whr + i4)); ghz += dot4(hv, ld4(whz + i4)); ghn += dot4(hv, ld4(whn + i4));
  }
  float r = 1.f / (1.f + __expf(-(gir + ghr)));
  float z = 1.f / (1.f + __expf(-(giz + ghz)));
  float n = tanhf(gin + r * ghn);
  float ns = (1.f - z) * n + z * h;

  // LN over the new slot row
  float s1 = ns, s2 = ns * ns;
#pragma unroll
  for (int off = 32; off >= 1; off >>= 1) { s1 += __shfl_down(s1, off); s2 += __shfl_down(s2, off); }
  if ((d & 63) == 0) { red4[(d >> 6) * 2] = s1; red4[(d >> 6) * 2 + 1] = s2; }
  __syncthreads();
  float sum = red4[0] + red4[2], sumsq = red4[1] + red4[3];
  float mean = sum * (1.f / 128.f);
  float var = sumsq * (1.f / 128.f) - mean * mean;
  float rs = rsqrtf(var + 1e-5f);
  lns[d] = (ns - mean) * rs * gff[d] + bff[d];
  __syncthreads();

  float a0 = b1[d], a1 = b1[d + 128];
  const float* w1a = W1 + d * D_;
  const float* w1b = W1 + (128 + d) * D_;
  for (int i4 = 0; i4 < D_; i4 += 4) {
    float4 lv = *reinterpret_cast<const float4*>(&lns[i4]);
    a0 += dot4(lv, ld4(w1a + i4));
    a1 += dot4(lv, ld4(w1b + i4));
  }
  h1s[d] = fmaxf(a0, 0.f);
  h1s[d + 128] = fmaxf(a1, 0.f);
  __syncthreads();

  float f = b2[d];
  const float* w2r = W2 + d * H_;
  for (int h4 = 0; h4 < H_; h4 += 4)
    f += dot4(*reinterpret_cast<const float4*>(&h1s[h4]), ld4(w2r + h4));
  slots[blk * D_ + d] = ns + f;
}

extern "C" void kernel_launch(void* const* d_in, const int* in_sizes, int n_in,
                              void* d_out, int out_size, void* d_ws, size_t ws_size,
                              hipStream_t stream) {
  const float* emb   = (const float*)d_in[0];
  const float* noise = (const float*)d_in[1];
  const float* mu    = (const float*)d_in[2];
  const float* sigma = (const float*)d_in[3];
  const float* Wk = (const float*)d_in[4];  const float* bk = (const float*)d_in[5];
  const float* Wq = (const float*)d_in[6];  const float* bq = (const float*)d_in[7];
  const float* Wv = (const float*)d_in[8];  const float* bv = (const float*)d_in[9];
  const float* Wih = (const float*)d_in[10]; const float* Whh = (const float*)d_in[11];
  const float* bih = (const float*)d_in[12]; const float* bhh = (const float*)d_in[13];
  const float* W1 = (const float*)d_in[14];  const float* b1 = (const float*)d_in[15];
  const float* W2 = (const float*)d_in[16];  const float* b2 = (const float*)d_in[17];
  const float* lin_g = (const float*)d_in[18]; const float* lin_b = (const float*)d_in[19];
  const float* ls_g  = (const float*)d_in[20]; const float* ls_b  = (const float*)d_in[21];
  const float* lff_g = (const float*)d_in[22]; const float* lff_b = (const float*)d_in[23];
  (void)bk;  // q.bk is softmax-invariant (cancels exactly)

  float* slots = (float*)d_out;  // [B,S,D] in d_out, updated in place
  float* qp       = (float*)d_ws;                          // 57,344 f   (q' = q@Wk)
  float* partialA = qp + (size_t)B_ * S_ * D_;             // 917,504 f  (unnormalized u chunks)
  float* partialM = partialA + (size_t)B_ * NCHUNK * S_ * D_;  // 7,168 f
  float* partialS = partialM + (size_t)B_ * NCHUNK * S_;       // 7,168 f

  k_init<<<224, 256, 0, stream>>>(noise, mu, sigma, slots);
  for (int it = 0; it < ITERS_; it++) {
    k_q<<<448, 128, 0, stream>>>(slots, Wq, bq, ls_g, ls_b, Wk, qp);
    k_attn<<<B_ * NCHUNK, 256, 0, stream>>>(qp, emb, lin_g, lin_b, partialA, partialM, partialS);
    k_gruff<<<448, 128, 0, stream>>>(partialA, partialM, partialS, slots, Wv, bv,
                                     Wih, Whh, bih, bhh, W1, b1, W2, b2, lff_g, lff_b);
  }
}

// Round 6
// 537.193 us; speedup vs baseline: 1.6644x; 1.0154x over previous
//
#include <hip/hip_runtime.h>
#include <math.h>

#define B_ 64
#define N_ 4096
#define D_ 128
#define S_ 7
#define H_ 256
#define ITERS_ 3
#define AP 132      // padded fp32 LDS row stride
#define NCHUNK 8    // j-chunks per batch (512 rows each) -> grid 512 = exactly 2 blocks/CU

__device__ __forceinline__ float dot4(float4 a, float4 b) {
  return a.x * b.x + a.y * b.y + a.z * b.z + a.w * b.w;
}
__device__ __forceinline__ float4 ld4(const float* p) {
  return *reinterpret_cast<const float4*>(p);
}

// ---------------- K0: slots = mu + sigma * noise ----------------
__global__ void k_init(const float* __restrict__ noise, const float* __restrict__ mu,
                       const float* __restrict__ sigma, float* __restrict__ slots) {
  int idx = blockIdx.x * 256 + threadIdx.x;  // 57344 total
  int d = idx & 127;
  slots[idx] = mu[d] + sigma[d] * noise[idx];
}

// ---------------- K2 (prologue only, it=0): q = LN(slots)@Wq^T + bq;  q' = q@Wk ----------------
// q' absorbs Wk so logits = q'.LN^T. The q.bk term is a per-(b,s) constant ->
// cancels exactly in softmax, so it is dropped.
__global__ __launch_bounds__(128) void k_q(
    const float* __restrict__ slots, const float* __restrict__ Wq, const float* __restrict__ bq,
    const float* __restrict__ g, const float* __restrict__ b,
    const float* __restrict__ Wk, float* __restrict__ qp) {
  __shared__ __align__(16) float lns[AP];
  __shared__ __align__(16) float qs2[AP];
  __shared__ float red[4];
  int row = blockIdx.x;  // b*7+s
  int d = threadIdx.x;
  float x = slots[row * D_ + d];
  float s1 = x, s2 = x * x;
#pragma unroll
  for (int off = 32; off >= 1; off >>= 1) { s1 += __shfl_down(s1, off); s2 += __shfl_down(s2, off); }
  if ((d & 63) == 0) { red[(d >> 6) * 2] = s1; red[(d >> 6) * 2 + 1] = s2; }
  __syncthreads();
  float sum = red[0] + red[2], sumsq = red[1] + red[3];
  float mean = sum * (1.f / 128.f);
  float var = sumsq * (1.f / 128.f) - mean * mean;
  float rs = rsqrtf(var + 1e-5f);
  lns[d] = (x - mean) * rs * g[d] + b[d];
  __syncthreads();
  const float* w = Wq + d * D_;
  float acc = bq[d];
  for (int i4 = 0; i4 < D_; i4 += 4) acc += dot4(*reinterpret_cast<const float4*>(&lns[i4]), ld4(w + i4));
  qs2[d] = acc;
  __syncthreads();
  float qpa = 0.f;
#pragma unroll 4
  for (int dd = 0; dd < D_; dd++) qpa += qs2[dd] * Wk[dd * D_ + d];
  qp[row * D_ + d] = qpa;
}

// ---------------- K3: fused LN + flash attention over one j-chunk of 512 ----------------
// LN(emb) is computed on the fly while staging each 64-row tile into LDS (the
// tile serves as both K and V). Online softmax per chunk; combine in k_gruffq.
__global__ __launch_bounds__(256) void k_attn(
    const float* __restrict__ qpbuf, const float* __restrict__ emb,
    const float* __restrict__ lng, const float* __restrict__ lnb,
    float* __restrict__ partialA, float* __restrict__ partialM, float* __restrict__ partialS) {
  __shared__ __align__(16) float qs[7 * AP];
  __shared__ __align__(16) float vt[64 * AP];   // LN tile (K and V); reused as redf at end
  __shared__ float red[28 * 64];                // logit partials [g*7+s][j]
  __shared__ float pt[7 * 64];                  // combined logits -> exp weights
  __shared__ float sm[7], ssum[7], tmax[7];
  int t = threadIdx.x;
  int b = blockIdx.x >> 3, jc = blockIdx.x & (NCHUNK - 1);

  if (t < 224) {
    int s = t >> 5, i4 = (t & 31) * 4;
    *reinterpret_cast<float4*>(&qs[s * AP + i4]) = ld4(&qpbuf[(b * 7 + s) * D_ + i4]);
  }
  if (t < 7) { sm[t] = -1e30f; ssum[t] = 0.f; }

  int j = t & 63, g = t >> 6, ib = g * 32;      // logits roles
  int d4 = (t & 31) * 4, jg = t >> 5;           // update roles
  int ln_i4 = (t & 31) * 4;
  int ln_r8 = t >> 5;
  float4 gv = ld4(&lng[ln_i4]);
  float4 bv4 = ld4(&lnb[ln_i4]);

  float acc[7][4];
#pragma unroll
  for (int s = 0; s < 7; s++)
#pragma unroll
    for (int c = 0; c < 4; c++) acc[s][c] = 0.f;
  __syncthreads();

  for (int sub = 0; sub < 8; sub++) {
    int j0 = jc * 512 + sub * 64;
    // stage + LN: 32 contiguous half-wave threads own one row
#pragma unroll
    for (int u = 0; u < 8; u++) {
      int row = u * 8 + ln_r8;
      float4 x = ld4(&emb[((long)b * N_ + j0 + row) * D_ + ln_i4]);
      float s1 = x.x + x.y + x.z + x.w;
      float s2 = dot4(x, x);
#pragma unroll
      for (int off = 16; off >= 1; off >>= 1) {
        s1 += __shfl_xor(s1, off, 32);
        s2 += __shfl_xor(s2, off, 32);
      }
      float mean = s1 * (1.f / 128.f);
      float var = s2 * (1.f / 128.f) - mean * mean;
      float rs = rsqrtf(var + 1e-5f);
      float4 o;
      o.x = (x.x - mean) * rs * gv.x + bv4.x;
      o.y = (x.y - mean) * rs * gv.y + bv4.y;
      o.z = (x.z - mean) * rs * gv.z + bv4.z;
      o.w = (x.w - mean) * rs * gv.w + bv4.w;
      *reinterpret_cast<float4*>(&vt[row * AP + ln_i4]) = o;
    }
    __syncthreads();

    // logits partial dots (same tree as before)
    float acc7[7];
#pragma unroll
    for (int s = 0; s < 7; s++) acc7[s] = 0.f;
#pragma unroll
    for (int st = 0; st < 8; st++) {
      float4 kv = *reinterpret_cast<const float4*>(&vt[j * AP + ib + st * 4]);
#pragma unroll
      for (int s = 0; s < 7; s++) {
        float4 qv = *reinterpret_cast<const float4*>(&qs[s * AP + ib + st * 4]);
        acc7[s] += dot4(kv, qv);
      }
    }
#pragma unroll
    for (int s = 0; s < 7; s++) red[(g * 7 + s) * 64 + j] = acc7[s];
    __syncthreads();

    // combine 4 partials -> raw logits (identical sum order)
    for (int pp = t; pp < 448; pp += 256) {
      int s = pp >> 6, jj = pp & 63;
      pt[pp] = red[s * 64 + jj] + red[(7 + s) * 64 + jj] +
               red[(14 + s) * 64 + jj] + red[(21 + s) * 64 + jj];
    }
    __syncthreads();

    // tile max per s
    if (t < 224) {
      int s = t >> 5, i = t & 31;
      float m = fmaxf(pt[s * 64 + i], pt[s * 64 + 32 + i]);
#pragma unroll
      for (int off = 16; off >= 1; off >>= 1) m = fmaxf(m, __shfl_down(m, off, 32));
      if ((t & 31) == 0) tmax[s] = m;
    }
    __syncthreads();

    // rescale acc by exp(m_old - m_new)
#pragma unroll
    for (int s = 0; s < 7; s++) {
      float mnew = fmaxf(sm[s], tmax[s]);
      float scl = __expf(sm[s] - mnew);
#pragma unroll
      for (int c = 0; c < 4; c++) acc[s][c] *= scl;
    }
    for (int pp = t; pp < 448; pp += 256) {
      int s = pp >> 6;
      float mnew = fmaxf(sm[s], tmax[s]);
      pt[pp] = __expf(pt[pp] - mnew);
    }
    __syncthreads();

    // chunk sum + state update
    if (t < 224) {
      int s = t >> 5, i = t & 31;
      float ssub = pt[s * 64 + i] + pt[s * 64 + 32 + i];
#pragma unroll
      for (int off = 16; off >= 1; off >>= 1) ssub += __shfl_down(ssub, off, 32);
      if ((t & 31) == 0) {
        float mnew = fmaxf(sm[s], tmax[s]);
        float scl = __expf(sm[s] - mnew);
        ssum[s] = ssum[s] * scl + ssub;
        sm[s] = mnew;
      }
    }

    // V-accumulate
#pragma unroll
    for (int jl = 0; jl < 8; jl++) {
      int jj = jg * 8 + jl;
      float4 vv = *reinterpret_cast<const float4*>(&vt[jj * AP + d4]);
#pragma unroll
      for (int s = 0; s < 7; s++) {
        float e = pt[s * 64 + jj];
        acc[s][0] += e * vv.x; acc[s][1] += e * vv.y;
        acc[s][2] += e * vv.z; acc[s][3] += e * vv.w;
      }
    }
    __syncthreads();
  }

  // cross-jg reduction (reuse vt)
  float* redf = vt;
#pragma unroll
  for (int s = 0; s < 7; s++)
    *reinterpret_cast<float4*>(&redf[(jg * 7 + s) * 128 + d4]) =
        make_float4(acc[s][0], acc[s][1], acc[s][2], acc[s][3]);
  __syncthreads();
  for (int pp = t; pp < 896; pp += 256) {
    int s = pp >> 7, d = pp & 127;
    float x = 0.f;
#pragma unroll
    for (int g2 = 0; g2 < 8; g2++) x += redf[(g2 * 7 + s) * 128 + d];
    partialA[((long)(b * NCHUNK + jc) * 7 + s) * 128 + d] = x;
  }
  if (t < 7) {
    partialM[(b * NCHUNK + jc) * 7 + t] = sm[t];
    partialS[(b * NCHUNK + jc) * 7 + t] = ssum[t];
  }
}

// ---------------- K4: flash combine + Wv epilogue + GRU + LN + FFN + fused next-q ----------------
// 256 threads: d = t&127, h = t>>7. Every long dot is split (3 dots/thread for
// GRU, split-K halves elsewhere) to halve the latency chain of the old 128-thread version.
__global__ __launch_bounds__(256) void k_gruffq(
    const float* __restrict__ partialA, const float* __restrict__ partialM,
    const float* __restrict__ partialS, float* __restrict__ slots,
    const float* __restrict__ Wv, const float* __restrict__ bv,
    const float* __restrict__ Wih, const float* __restrict__ Whh,
    const float* __restrict__ bih, const float* __restrict__ bhh,
    const float* __restrict__ W1, const float* __restrict__ b1,
    const float* __restrict__ W2, const float* __restrict__ b2,
    const float* __restrict__ gff, const float* __restrict__ bff,
    const float* __restrict__ lsg, const float* __restrict__ lsb,
    const float* __restrict__ Wq, const float* __restrict__ bq,
    const float* __restrict__ Wk, float* __restrict__ qp, int compute_q) {
  __shared__ __align__(16) float us[AP];
  __shared__ __align__(16) float xs[AP];
  __shared__ __align__(16) float hs[AP];
  __shared__ __align__(16) float nss[AP];
  __shared__ __align__(16) float lns[AP];
  __shared__ __align__(16) float sn[AP];
  __shared__ __align__(16) float qv[AP];
  __shared__ __align__(16) float h1s[H_];
  __shared__ __align__(16) float g6[6 * 128];
  __shared__ __align__(16) float pp[2 * 128];
  __shared__ float den2[2];
  __shared__ float red2[2];
  int t = threadIdx.x;
  int d = t & 127, h = t >> 7;
  int blk = blockIdx.x;
  int b = blk / 7, s = blk % 7;

  // ---- flash combine over NCHUNK chunks (split across h) ----
  float mg = -1e30f;
#pragma unroll
  for (int c = 0; c < NCHUNK; c++) mg = fmaxf(mg, partialM[(b * NCHUNK + c) * 7 + s]);
  float up = 0.f, den = 0.f;
#pragma unroll
  for (int cc = 0; cc < NCHUNK / 2; cc++) {
    int c = h * (NCHUNK / 2) + cc;
    float w = __expf(partialM[(b * NCHUNK + c) * 7 + s] - mg);
    den += w * partialS[(b * NCHUNK + c) * 7 + s];
    up += w * partialA[((long)(b * NCHUNK + c) * 7 + s) * 128 + d];
  }
  pp[h * 128 + d] = up;
  if (d == 0) den2[h] = den;
  if (h == 1) hs[d] = slots[blk * D_ + d];
  __syncthreads();
  if (h == 0) us[d] = (pp[d] + pp[128 + d]) / (den2[0] + den2[1]);
  __syncthreads();

  // ---- updates x = bv + us . Wv[d,:]  (split-K) ----
  {
    const float* wvr = Wv + d * D_ + h * 64;
    float acc = 0.f;
    for (int i4 = 0; i4 < 64; i4 += 4)
      acc += dot4(*reinterpret_cast<const float4*>(&us[h * 64 + i4]), ld4(wvr + i4));
    pp[h * 128 + d] = acc;
  }
  __syncthreads();
  if (h == 0) xs[d] = bv[d] + pp[d] + pp[128 + d];
  __syncthreads();

  // ---- GRU: h==0 computes gi (3 dots over xs), h==1 computes gh (3 dots over hs) ----
  {
    const float* base = (h == 0) ? Wih : Whh;
    const float* bias = (h == 0) ? bih : bhh;
    const float* vec = (h == 0) ? xs : hs;
    float a0 = bias[d], a1 = bias[128 + d], a2 = bias[256 + d];
    const float* w0 = base + d * D_;
    const float* w1 = base + (128 + d) * D_;
    const float* w2 = base + (256 + d) * D_;
    for (int i4 = 0; i4 < D_; i4 += 4) {
      float4 v = *reinterpret_cast<const float4*>(&vec[i4]);
      a0 += dot4(v, ld4(w0 + i4));
      a1 += dot4(v, ld4(w1 + i4));
      a2 += dot4(v, ld4(w2 + i4));
    }
    g6[(h * 3 + 0) * 128 + d] = a0;
    g6[(h * 3 + 1) * 128 + d] = a1;
    g6[(h * 3 + 2) * 128 + d] = a2;
  }
  __syncthreads();
  if (h == 0) {
    float gir = g6[d], giz = g6[128 + d], gin = g6[256 + d];
    float ghr = g6[384 + d], ghz = g6[512 + d], ghn = g6[640 + d];
    float r = 1.f / (1.f + __expf(-(gir + ghr)));
    float z = 1.f / (1.f + __expf(-(giz + ghz)));
    float n = tanhf(gin + r * ghn);
    nss[d] = (1.f - z) * n + z * hs[d];
  }
  __syncthreads();

  // ---- LN_ff over nss (wave 0 computes stats) ----
  if (t < 64) {
    float v0 = nss[t], v1 = nss[t + 64];
    float s1 = v0 + v1, s2 = v0 * v0 + v1 * v1;
#pragma unroll
    for (int off = 32; off >= 1; off >>= 1) { s1 += __shfl_down(s1, off); s2 += __shfl_down(s2, off); }
    if (t == 0) { red2[0] = s1; red2[1] = s2; }
  }
  __syncthreads();
  {
    float mean = red2[0] * (1.f / 128.f);
    float var = red2[1] * (1.f / 128.f) - mean * mean;
    float rs = rsqrtf(var + 1e-5f);
    if (h == 0) lns[d] = (nss[d] - mean) * rs * gff[d] + bff[d];
  }
  __syncthreads();

  // ---- FFN1: 256 outputs, one per thread ----
  {
    float a = b1[t];
    const float* w = W1 + t * D_;
    for (int i4 = 0; i4 < D_; i4 += 4)
      a += dot4(*reinterpret_cast<const float4*>(&lns[i4]), ld4(w + i4));
    h1s[t] = fmaxf(a, 0.f);
  }
  __syncthreads();

  // ---- FFN2 + residual (split-K) ----
  {
    const float* w2r = W2 + d * H_ + h * 128;
    float acc = 0.f;
    for (int h4 = 0; h4 < 128; h4 += 4)
      acc += dot4(*reinterpret_cast<const float4*>(&h1s[h * 128 + h4]), ld4(w2r + h4));
    pp[h * 128 + d] = acc;
  }
  __syncthreads();
  if (h == 0) {
    float out = nss[d] + b2[d] + pp[d] + pp[128 + d];
    sn[d] = out;
    slots[blk * D_ + d] = out;
  }
  __syncthreads();

  if (!compute_q) return;

  // ---- fused next-iteration q: LN_s(sn) -> q -> q' = q@Wk ----
  if (t < 64) {
    float v0 = sn[t], v1 = sn[t + 64];
    float s1 = v0 + v1, s2 = v0 * v0 + v1 * v1;
#pragma unroll
    for (int off = 32; off >= 1; off >>= 1) { s1 += __shfl_down(s1, off); s2 += __shfl_down(s2, off); }
    if (t == 0) { red2[0] = s1; red2[1] = s2; }
  }
  __syncthreads();
  {
    float mean = red2[0] * (1.f / 128.f);
    float var = red2[1] * (1.f / 128.f) - mean * mean;
    float rs = rsqrtf(var + 1e-5f);
    if (h == 0) lns[d] = (sn[d] - mean) * rs * lsg[d] + lsb[d];
  }
  __syncthreads();
  // q[d] = bq[d] + lns . Wq[d,:]  (split-K)
  {
    const float* w = Wq + d * D_ + h * 64;
    float acc = 0.f;
    for (int i4 = 0; i4 < 64; i4 += 4)
      acc += dot4(*reinterpret_cast<const float4*>(&lns[h * 64 + i4]), ld4(w + i4));
    pp[h * 128 + d] = acc;
  }
  __syncthreads();
  if (h == 0) qv[d] = bq[d] + pp[d] + pp[128 + d];
  __syncthreads();
  // q'[d] = sum_dd qv[dd] * Wk[dd][d]  (split over dd halves; column reads coalesced)
  {
    float acc = 0.f;
    const float* wc = Wk + h * 64 * D_ + d;
#pragma unroll 4
    for (int dd = 0; dd < 64; dd++) acc += qv[h * 64 + dd] * wc[dd * D_];
    pp[h * 128 + d] = acc;
  }
  __syncthreads();
  if (h == 0) qp[blk * D_ + d] = pp[d] + pp[128 + d];
}

extern "C" void kernel_launch(void* const* d_in, const int* in_sizes, int n_in,
                              void* d_out, int out_size, void* d_ws, size_t ws_size,
                              hipStream_t stream) {
  const float* emb   = (const float*)d_in[0];
  const float* noise = (const float*)d_in[1];
  const float* mu    = (const float*)d_in[2];
  const float* sigma = (const float*)d_in[3];
  const float* Wk = (const float*)d_in[4];  const float* bk = (const float*)d_in[5];
  const float* Wq = (const float*)d_in[6];  const float* bq = (const float*)d_in[7];
  const float* Wv = (const float*)d_in[8];  const float* bv = (const float*)d_in[9];
  const float* Wih = (const float*)d_in[10]; const float* Whh = (const float*)d_in[11];
  const float* bih = (const float*)d_in[12]; const float* bhh = (const float*)d_in[13];
  const float* W1 = (const float*)d_in[14];  const float* b1 = (const float*)d_in[15];
  const float* W2 = (const float*)d_in[16];  const float* b2 = (const float*)d_in[17];
  const float* lin_g = (const float*)d_in[18]; const float* lin_b = (const float*)d_in[19];
  const float* ls_g  = (const float*)d_in[20]; const float* ls_b  = (const float*)d_in[21];
  const float* lff_g = (const float*)d_in[22]; const float* lff_b = (const float*)d_in[23];
  (void)bk;  // q.bk is softmax-invariant (cancels exactly)

  float* slots = (float*)d_out;  // [B,S,D] in d_out, updated in place
  float* qp       = (float*)d_ws;                              // 57,344 f   (q' = q@Wk)
  float* partialA = qp + (size_t)B_ * S_ * D_;                 // 458,752 f  (unnormalized u chunks)
  float* partialM = partialA + (size_t)B_ * NCHUNK * S_ * D_;  // 3,584 f
  float* partialS = partialM + (size_t)B_ * NCHUNK * S_;       // 3,584 f

  k_init<<<224, 256, 0, stream>>>(noise, mu, sigma, slots);
  k_q<<<448, 128, 0, stream>>>(slots, Wq, bq, ls_g, ls_b, Wk, qp);
  for (int it = 0; it < ITERS_; it++) {
    k_attn<<<B_ * NCHUNK, 256, 0, stream>>>(qp, emb, lin_g, lin_b, partialA, partialM, partialS);
    k_gruffq<<<448, 256, 0, stream>>>(partialA, partialM, partialS, slots, Wv, bv,
                                      Wih, Whh, bih, bhh, W1, b1, W2, b2, lff_g, lff_b,
                                      ls_g, ls_b, Wq, bq, Wk, qp, it < ITERS_ - 1 ? 1 : 0);
  }
}